// Round 13
// baseline (321.329 us; speedup 1.0000x reference)
//
#include <hip/hip_runtime.h>

#define N_NODES 20000
#define N_EDGES 640000
#define N_MT (N_EDGES/16)   // 40000 microtiles of 16 edges

typedef short short8 __attribute__((ext_vector_type(8)));
typedef float f32x4 __attribute__((ext_vector_type(4)));
typedef unsigned int u32x4 __attribute__((ext_vector_type(4)));

// RNE float -> bf16 bits
__device__ __forceinline__ unsigned int f2bf(float x){
  unsigned int u = __builtin_bit_cast(unsigned int, x);
  u += 0x7fffu + ((u >> 16) & 1u);
  return u >> 16;
}
__device__ __forceinline__ float bf2f(unsigned short u){
  unsigned int v = ((unsigned int)u) << 16;
  return __builtin_bit_cast(float, v);
}
// HW packed f32->bf16 (RNE, same rounding as f2bf for finite inputs):
// dst.lo = bf16(lo), dst.hi = bf16(hi). One instruction per PAIR.
__device__ __forceinline__ unsigned cvt_pk_bf16(float lo, float hi){
  unsigned d;
  asm("v_cvt_pk_bf16_f32 %0, %1, %2" : "=v"(d) : "v"(lo), "v"(hi));
  return d;
}

__device__ __forceinline__ void wave_lds_fence(){
  __asm__ volatile("s_waitcnt lgkmcnt(0)" ::: "memory");
}
__device__ __forceinline__ void wave_vm_fence(){
  __asm__ volatile("s_waitcnt vmcnt(0)" ::: "memory");
}

// async global->LDS, 16B per lane; LDS dest = uniform base + laneId*16
__device__ __forceinline__ void gload16(const void* g, void* l){
  __builtin_amdgcn_global_load_lds(
      (const __attribute__((address_space(1))) unsigned int*)g,
      (__attribute__((address_space(3))) unsigned int*)l,
      16, 0, 0);
}

#define HIST_BLOCKS 625                    // 4 edges/thread, int4 loads
#define YN_BLOCKS   (N_NODES/16)           // 1250 (16 nodes per block)
#define AGGZ_BLOCKS 938                    // zero 3,840,000 floats, 16/thread

// ---- fused: edge-dst histogram + y = l1 linear (bf16 out) + agg zeroing ----
__global__ void k_pre(const int* __restrict__ ei, int* __restrict__ counts,
                      const float* __restrict__ ni, const float* __restrict__ na,
                      const float* __restrict__ Wl10, const float* __restrict__ Wl11,
                      unsigned short* __restrict__ y, float4* __restrict__ aggz){
  if (blockIdx.x < HIST_BLOCKS){
    int i = blockIdx.x*256 + threadIdx.x;
    if (i < N_EDGES/4){
      int4 d4 = *(const int4*)(ei + N_EDGES + i*4);
      atomicAdd(&counts[d4.x], 1);
      atomicAdd(&counts[d4.y], 1);
      atomicAdd(&counts[d4.z], 1);
      atomicAdd(&counts[d4.w], 1);
    }
    return;
  }
  if (blockIdx.x >= HIST_BLOCKS + YN_BLOCKS){
    int i = (blockIdx.x - HIST_BLOCKS - YN_BLOCKS)*256 + threadIdx.x;
    if (i < 240000){
      float4 z = {0.f,0.f,0.f,0.f};
      float4* p = aggz + (size_t)i*4;
      p[0]=z; p[1]=z; p[2]=z; p[3]=z;
    }
    return;
  }
  __shared__ float sW0[1024];
  __shared__ float sW1[256];
  __shared__ float sni[16*84];
  __shared__ float sna[16];
  const int t = threadIdx.x;
  const int nb = (blockIdx.x - HIST_BLOCKS)*16;
  for (int i=t; i<1024; i+=256) sW0[i] = Wl10[i];
  if (t < 256) sW1[t] = Wl11[t];
  for (int i=t; i<320; i+=256){
    int n = i/20, q = i - n*20;
    *(float4*)&sni[n*84 + q*4] = *(const float4*)(ni + (size_t)(nb+n)*80 + q*4);
  }
  if (t < 16) sna[t] = na[nb + t];
  __syncthreads();
  for (int i=t; i<1280; i+=256){
    int n = i/80, k = i - n*80;
    const float* row = sni + n*84;
    float a = sna[n];
    float acc = 0.f;
    if (k < 32){
      #pragma unroll
      for (int u=0; u<32; ++u) acc += row[u]*sW0[u*32+k];
      y[(size_t)nb*80 + i] = (unsigned short)f2bf(acc * a * 0.17677669529663687f);
    } else {
      int kk = k-32, v = kk/3, ii = kk - v*3;
      #pragma unroll
      for (int u=0; u<16; ++u) acc += row[32+u*3+ii]*sW1[u*16+v];
      y[(size_t)nb*80 + i] = (unsigned short)f2bf(acc * a * 0.25f);
    }
  }
}

// block-level base allocation (one atomic per 256 nodes)
__global__ void k_alloc(const int* __restrict__ counts, int* __restrict__ ctr,
                        int* __restrict__ cursor){
  __shared__ int wsum[4];
  __shared__ int s_base;
  const int t = threadIdx.x;
  const int lane = t & 63, wv = t >> 6;
  const int n = blockIdx.x*256 + t;
  int v = (n < N_NODES) ? counts[n] : 0;
  int x = v;
  #pragma unroll
  for (int off=1; off<64; off<<=1){
    int sh = __shfl_up(x, off, 64);
    if (lane >= off) x += sh;
  }
  if (lane == 63) wsum[wv] = x;
  __syncthreads();
  if (t == 0){
    int s0 = wsum[0], s1 = wsum[1], s2 = wsum[2], s3 = wsum[3];
    int total = s0 + s1 + s2 + s3;
    wsum[0] = 0; wsum[1] = s0; wsum[2] = s0+s1; wsum[3] = s0+s1+s2;
    s_base = atomicAdd(ctr, total);
  }
  __syncthreads();
  if (n < N_NODES) cursor[n] = s_base + wsum[wv] + (x - v);
}

// One 32B record per edge at its sorted position (u16 view):
// [0..9]=es bf16, [10..13]=ea bf16, [14..15]=u32 (src<<16|dst)
// r17: float2/float4 vectorized source loads; PLAIN meta stores (nt stores
// evict meta from L2/L3 -> k_edge +21us; nt is a dead branch, r15/r16).
__global__ void k_fill(const int* __restrict__ ei, const float* __restrict__ ea,
                       const float* __restrict__ es, int* __restrict__ cursor,
                       u32x4* __restrict__ meta){
  int e = blockIdx.x*256 + threadIdx.x;
  if (e >= N_EDGES) return;
  int s = ei[e], d = ei[N_EDGES + e];
  int pos = atomicAdd(&cursor[d], 1);
  const float4 eav = *(const float4*)(ea + (size_t)e*4);
  const float2* esp2 = (const float2*)(es + (size_t)e*10);
  float2 f0 = esp2[0], f1 = esp2[1], f2 = esp2[2], f3 = esp2[3], f4 = esp2[4];
  u32x4 m0, m1;
  m0[0] = f2bf(f0.x) | (f2bf(f0.y)<<16);
  m0[1] = f2bf(f1.x) | (f2bf(f1.y)<<16);
  m0[2] = f2bf(f2.x) | (f2bf(f2.y)<<16);
  m0[3] = f2bf(f3.x) | (f2bf(f3.y)<<16);
  m1[0] = f2bf(f4.x) | (f2bf(f4.y)<<16);
  m1[1] = f2bf(eav.x) | (f2bf(eav.y)<<16);
  m1[2] = f2bf(eav.z) | (f2bf(eav.w)<<16);
  m1[3] = ((unsigned int)s << 16) | (unsigned int)d;
  u32x4* mp = meta + (size_t)pos*2;
  mp[0] = m0;
  mp[1] = m1;
}

// ---------------- fused edge MLP + messages + segment-sum ----------------
// r0 pipeline + r19 transposed s_w + r20 tail-readlane + r21 two-pass
// e-loop + r22 HW BF16 PACK: the 40 hand-rolled f2bf RNE conversions per
// tile (24 MFMA-pack + 16 silu-pack, 3-4 int ops each) become 20
// v_cvt_pk_bf16_f32 (1 instr per pair, same RNE rounding). ~120 fewer
// VALU ops/tile; we are issue-bound now (VALUBusy 67.7% at 3 waves/SIMD).
// Ledger:
//  - transposed s_w (r19): 116->113, conflicts 2.96M->1.04M. CONFIRMED.
//  - tail-readlane (r20): total 319->314.7, conflicts ->560K. CONFIRMED.
//  - two-pass e-loop (r21): profiled k_edge 113->107.5 full-clock,
//    VALUBusy ->67.7; total neutral. KEPT (kernel-level win).
//  - deferred atomic flush (r18): 116->119. vmcnt(0) NOT ack-stalled. DEAD.
//  - nt meta stores upstream: 117->138 (meta must stay L2-resident). DEAD.
//  - deep meta rotation + vmcnt(1) + sched_barrier(0): ->151. DEAD.
//  - DO NOT exec-mask global_load_lds (r11/r13: 117->164us).
//  - grid must stay 768 (3 blocks/CU; 1024 runs as two phases).
//  - NO waves-per-EU hint (r9/r10: VGPR squeeze -> scratch spills).
__global__ __launch_bounds__(256) void k_edge(
    const uint2* __restrict__ meta,
    const float* __restrict__ Wfc0, const float* __restrict__ Wfc1,
    const unsigned short* __restrict__ yb, float* __restrict__ agg){
  __shared__ float s_wfc0[640];                            // [k=10][n=64] f32
  __shared__ __align__(16) unsigned short s_w[4][96*20];   // per-wave [o][e] bf16, stride 20
  __shared__ __align__(16) unsigned short s_y[4][2][16*96];// dbuf y rows, stride 96 u16 (192B=12 chunks)
  __shared__ __align__(16) unsigned int  s_m[4][2][16*8];  // dbuf raw 32B records

  const int t = threadIdx.x;
  const int w = t >> 6, l = t & 63;
  const int r = l & 15, part = l >> 4;

  for (int i = t; i < 640; i += 256) s_wfc0[i] = Wfc0[i];

  // B-fragments of Wfc1 (bf16) in registers
  short8 b0[6], b1[6];
  #pragma unroll
  for (int nt=0; nt<6; ++nt){
    #pragma unroll
    for (int j=0; j<8; ++j){
      b0[nt][j] = (short)f2bf(Wfc1[(     part*8+j)*96 + nt*16 + r]);
      b1[nt][j] = (short)f2bf(Wfc1[(32 + part*8+j)*96 + nt*16 + r]);
    }
  }
  __syncthreads();   // only block barrier: s_wfc0 ready

  // per-lane message-channel constants
  int o_c[3], yo[3], eai[3];
  #pragma unroll
  for (int p=0; p<3; ++p){
    int c = p*64 + l;
    if (c < 32)      { o_c[p]=c;    yo[p]=c;        eai[p]=0; }
    else if (c < 48) { int u=c-32;  o_c[p]=80+u;    yo[p]=32+3*u; eai[p]=0; }
    else if (c < 144){ int idx=c-48;  int u=idx/3, fi=idx-u*3; o_c[p]=32+u; yo[p]=u;        eai[p]=1+fi; }
    else             { int idx=c-144; int u=idx/3, i =idx-u*3; o_c[p]=64+u; yo[p]=32+3*u+i; eai[p]=0; }
  }
  const bool dot0 = (l >= 32) && (l < 48);
  // ea shift-select precompute: word = eai>>1 (0:ea01,1:ea23), shamt=(eai&1)*16
  unsigned sh_[3]; bool whi_[3];
  #pragma unroll
  for (int p=0; p<3; ++p){ sh_[p] = (unsigned)((eai[p]&1)*16); whi_[p] = (eai[p]>>1)!=0; }

  unsigned short* sw = s_w[w];

  // y chunk assignment: instr i, lane l -> chunk idx=i*64+l; row=idx/12,
  // chunk-in-row byte offset = (idx%12)*16 (rows padded 160B->192B)
  int row_i[3], cir_i[3];
  #pragma unroll
  for (int i=0; i<3; ++i){
    int idx = i*64 + l;
    row_i[i] = idx/12;
    cir_i[i] = (idx - 12*row_i[i])*16;
  }

  const int gw = blockIdx.x*4 + w;
  const int nw = gridDim.x*4;
  const int m0 = (int)(((long long)gw     * N_MT) / nw);
  const int m1 = (int)(((long long)(gw+1) * N_MT) / nw);
  if (m0 >= m1) return;

  // ---- prologue: stage tile m0 into buffer 0
  uint2 mreg = meta[(size_t)m0*64 + l];
  {
    unsigned short* syn = s_y[w][0];
    #pragma unroll
    for (int i=0; i<3; ++i){
      int pk = __shfl((int)mreg.y, 4*row_i[i] + 3);
      unsigned src = ((unsigned)pk) >> 16;
      gload16((const char*)yb + (size_t)src*160 + cir_i[i], (char*)syn + i*1024);
    }
    *(uint2*)(&s_m[w][0][(l>>2)*8 + (l&3)*2]) = mreg;
  }
  mreg = meta[(size_t)((m0+1 < m1) ? m0+1 : m1-1)*64 + l];

  float acc0 = 0.f, acc1 = 0.f, acc2 = 0.f;
  int dcur = -1;
  int b = 0;

  for (int m = m0; m < m1; ++m){
    // ---- y(m) landed in s_y[b]; mreg = meta(m+1) ready
    wave_vm_fence();
    const int nb2 = b ^ 1;
    // ---- issue tile m+1 staging (DMA y -> s_y[nb2], raw meta -> s_m[nb2])
    {
      unsigned short* syn = s_y[w][nb2];
      #pragma unroll
      for (int i=0; i<3; ++i){
        int pk = __shfl((int)mreg.y, 4*row_i[i] + 3);
        unsigned src = ((unsigned)pk) >> 16;
        gload16((const char*)yb + (size_t)src*160 + cir_i[i], (char*)syn + i*1024);
      }
      *(uint2*)(&s_m[w][nb2][(l>>2)*8 + (l&3)*2]) = mreg;
    }
    // ---- prefetch meta(m+2)
    {
      int mnx = (m+2 < m1) ? m+2 : m1-1;
      mreg = meta[(size_t)mnx*64 + l];
    }
    wave_lds_fence();   // s_m writes visible (covers prologue on first iter)

    const unsigned int* smu = s_m[w][b];
    const unsigned short* syb = s_y[w][b];

    // ---- per-lane tail preload: edge (l&15) words 4..7 (16B aligned)
    u32x4 tail = *(const u32x4*)(smu + (l&15)*8 + 4);

    // ---- layer1: h[r][part*8+j] from raw record es (bf16)
    const unsigned short* esr = (const unsigned short*)(smu + r*8);
    float hv0[8], hv1[8];
    #pragma unroll
    for (int j=0; j<8; ++j){ hv0[j]=0.f; hv1[j]=0.f; }
    #pragma unroll
    for (int k=0; k<10; ++k){
      float ev = bf2f(esr[k]);
      const float* wr = s_wfc0 + k*64 + part*8;
      #pragma unroll
      for (int j=0; j<8; ++j){ hv0[j] += ev*wr[j]; hv1[j] += ev*wr[32+j]; }
    }
    // silu + HW pack (8 cvt_pk instead of 16 f2bf)
    float sg0[8], sg1[8];
    #pragma unroll
    for (int j=0; j<8; ++j){
      float x0 = hv0[j]*0.31622776601683794f;   // /sqrt(10)
      float x1 = hv1[j]*0.31622776601683794f;
      sg0[j] = x0/(1.f+__expf(-x0));
      sg1[j] = x1/(1.f+__expf(-x1));
    }
    u32x4 aw0, aw1;
    #pragma unroll
    for (int j2=0; j2<4; ++j2){
      aw0[j2] = cvt_pk_bf16(sg0[2*j2], sg0[2*j2+1]);
      aw1[j2] = cvt_pk_bf16(sg1[2*j2], sg1[2*j2+1]);
    }
    short8 a0 = __builtin_bit_cast(short8, aw0);
    short8 a1 = __builtin_bit_cast(short8, aw1);

    // ---- layer2 MFMA: transposed store w[o=nt*16+r][e=part*4+rr]
    // pack via 2 cvt_pk (was 4 f2bf)
    #pragma unroll
    for (int nt=0; nt<6; ++nt){
      f32x4 acc = {0.f,0.f,0.f,0.f};
      acc = __builtin_amdgcn_mfma_f32_16x16x32_bf16(a0, b0[nt], acc, 0,0,0);
      acc = __builtin_amdgcn_mfma_f32_16x16x32_bf16(a1, b1[nt], acc, 0,0,0);
      uint2 pkd;
      pkd.x = cvt_pk_bf16(acc[0]*0.125f, acc[1]*0.125f);
      pkd.y = cvt_pk_bf16(acc[2]*0.125f, acc[3]*0.125f);
      *(uint2*)(&sw[(nt*16+r)*20 + part*4]) = pkd;
    }
    wave_lds_fence();   // s_w visible

    // ---- preload this lane's 3 w-channel rows into registers
    unsigned int wr0[8], wr1[8], wr2[8];
    {
      const uint2* q0 = (const uint2*)(sw + o_c[0]*20);
      const uint2* q1 = (const uint2*)(sw + o_c[1]*20);
      const uint2* q2 = (const uint2*)(sw + o_c[2]*20);
      uint2 a, bb, c, d;
      a=q0[0]; bb=q0[1]; c=q0[2]; d=q0[3];
      wr0[0]=a.x; wr0[1]=a.y; wr0[2]=bb.x; wr0[3]=bb.y;
      wr0[4]=c.x; wr0[5]=c.y; wr0[6]=d.x; wr0[7]=d.y;
      a=q1[0]; bb=q1[1]; c=q1[2]; d=q1[3];
      wr1[0]=a.x; wr1[1]=a.y; wr1[2]=bb.x; wr1[3]=bb.y;
      wr1[4]=c.x; wr1[5]=c.y; wr1[6]=d.x; wr1[7]=d.y;
      a=q2[0]; bb=q2[1]; c=q2[2]; d=q2[3];
      wr2[0]=a.x; wr2[1]=a.y; wr2[2]=bb.x; wr2[3]=bb.y;
      wr2[4]=c.x; wr2[5]=c.y; wr2[6]=d.x; wr2[7]=d.y;
    }

    // ---- pass 1: branch-free per-edge messages into registers.
    // 48 y-reads share 3 base addrs + imm offsets -> burst-issue.
    float msg0[16], msg1[16], msg2[16];
    #pragma unroll
    for (int e=0; e<16; ++e){
      unsigned ea01 = (unsigned)__builtin_amdgcn_readlane((int)tail[1], e);
      unsigned ea23 = (unsigned)__builtin_amdgcn_readlane((int)tail[2], e);
      const unsigned short* sye = syb + e*96;
      float wv0 = bf2f((e&1) ? (unsigned short)(wr0[e>>1]>>16) : (unsigned short)wr0[e>>1]);
      float wv1 = bf2f((e&1) ? (unsigned short)(wr1[e>>1]>>16) : (unsigned short)wr1[e>>1]);
      float wv2 = bf2f((e&1) ? (unsigned short)(wr2[e>>1]>>16) : (unsigned short)wr2[e>>1]);
      unsigned ew0 = whi_[0] ? ea23 : ea01;
      unsigned ew1 = whi_[1] ? ea23 : ea01;
      unsigned ew2 = whi_[2] ? ea23 : ea01;
      float ea0f = __builtin_bit_cast(float, (ew0 >> sh_[0]) << 16);
      float ea1f = __builtin_bit_cast(float, (ew1 >> sh_[1]) << 16);
      float ea2f = __builtin_bit_cast(float, (ew2 >> sh_[2]) << 16);
      float m0v;
      if (dot0){
        float e1f = __builtin_bit_cast(float, ea01 & 0xffff0000u);
        float e2f = __builtin_bit_cast(float, ea23 << 16);
        float e3f = __builtin_bit_cast(float, ea23 & 0xffff0000u);
        m0v = wv0 *
              (bf2f(sye[yo[0]])*e1f + bf2f(sye[yo[0]+1])*e2f
               + bf2f(sye[yo[0]+2])*e3f)
              * 0.5773502691896258f;   // /sqrt(3)
      } else {
        m0v = wv0 * bf2f(sye[yo[0]]) * ea0f;
      }
      msg0[e] = m0v;
      msg1[e] = wv1 * bf2f(sye[yo[1]]) * ea1f;
      msg2[e] = wv2 * bf2f(sye[yo[2]]) * ea2f;
    }

    // ---- pass 2: LDS-free segment-sum (scalar branch, register adds)
    #pragma unroll
    for (int e=0; e<16; ++e){
      unsigned sdw = (unsigned)__builtin_amdgcn_readlane((int)tail[3], e);
      int de = (int)(sdw & 0xffffu);
      if (de != dcur){
        if (dcur >= 0){
          unsafeAtomicAdd(&agg[(size_t)dcur*192 +       l], acc0);
          unsafeAtomicAdd(&agg[(size_t)dcur*192 +  64 + l], acc1);
          unsafeAtomicAdd(&agg[(size_t)dcur*192 + 128 + l], acc2);
        }
        acc0 = acc1 = acc2 = 0.f;
        dcur = de;
      }
      acc0 += msg0[e];
      acc1 += msg1[e];
      acc2 += msg2[e];
    }

    b = nb2;
  }
  if (dcur >= 0){
    unsafeAtomicAdd(&agg[(size_t)dcur*192 +       l], acc0);
    unsafeAtomicAdd(&agg[(size_t)dcur*192 +  64 + l], acc1);
    unsafeAtomicAdd(&agg[(size_t)dcur*192 + 128 + l], acc2);
  }
}

// ---------------- finish: z = agg @ W_l2, out = c_s*s + c_x*z ----------------
__global__ void k_finish(const float* __restrict__ ni, const float* __restrict__ na,
    const float* __restrict__ Wsc0, const float* __restrict__ Wsc1,
    const float* __restrict__ Wl20, const float* __restrict__ Wl21,
    const float* __restrict__ agg, float* __restrict__ out){
  __shared__ float sWsc0[1024];
  __shared__ float sWsc1[256];
  __shared__ float sWl20[1536];
  __shared__ float sWl21[768];
  __shared__ float sni[16*84];
  __shared__ float sag[16*196];
  __shared__ float sna[16];
  const int t = threadIdx.x;
  const int nb = blockIdx.x*16;
  for (int i=t; i<1024; i+=256) sWsc0[i] = Wsc0[i];
  if (t < 256) sWsc1[t] = Wsc1[t];
  for (int i=t; i<1536; i+=256) sWl20[i] = Wl20[i];
  for (int i=t; i<768;  i+=256) sWl21[i] = Wl21[i];
  for (int i=t; i<320;  i+=256){
    int n = i/20, q = i - n*20;
    *(float4*)&sni[n*84 + q*4] = *(const float4*)(ni + (size_t)(nb+n)*80 + q*4);
  }
  for (int i=t; i<768;  i+=256){
    int n = i/48, q = i - n*48;
    *(float4*)&sag[n*196 + q*4] = *(const float4*)(agg + (size_t)(nb+n)*192 + q*4);
  }
  if (t < 16) sna[t] = na[nb + t];
  __syncthreads();

  const float c_s = 0.3826834323650898f;   // sin(pi/8)
  const float c_x = 0.9238795325112867f;   // cos(pi/8)
  const float zscale = 0.17677669529663687f * 0.14433756729740643f;
  for (int i=t; i<1280; i+=256){
    int n = i/80, k = i - n*80;
    const float* row = sni + n*84;
    const float* ag  = sag + n*196;
    float a = sna[n];
    float s = 0.f, z = 0.f;
    if (k < 32){
      #pragma unroll
      for (int u=0; u<32; ++u) s += row[u]*sWsc0[u*32+k];
      s *= a * 0.17677669529663687f;
      #pragma unroll
      for (int u=0; u<48; ++u) z += ag[u]*sWl20[u*32+k];
    } else {
      int kk=k-32, v=kk/3, ii=kk-v*3;
      #pragma unroll
      for (int u=0; u<16; ++u) s += row[32+u*3+ii]*sWsc1[u*16+v];
      s *= a * 0.25f;
      #pragma unroll
      for (int u=0; u<48; ++u) z += ag[48+u*3+ii]*sWl21[u*16+v];
    }
    out[(size_t)nb*80 + i] = c_s*s + c_x*z*zscale;
  }
}

extern "C" void kernel_launch(void* const* d_in, const int* in_sizes, int n_in,
                              void* d_out, int out_size, void* d_ws, size_t ws_size,
                              hipStream_t stream){
  const float* node_input   = (const float*)d_in[0];
  const float* node_attr    = (const float*)d_in[1];
  const float* edge_attr    = (const float*)d_in[2];
  const float* edge_scalars = (const float*)d_in[3];
  const float* W_sc0 = (const float*)d_in[4];
  const float* W_sc1 = (const float*)d_in[5];
  const float* W_l1_0 = (const float*)d_in[6];
  const float* W_l1_1 = (const float*)d_in[7];
  const float* W_fc0 = (const float*)d_in[8];
  const float* W_fc1 = (const float*)d_in[9];
  const float* W_l2_0 = (const float*)d_in[10];
  const float* W_l2_1 = (const float*)d_in[11];
  const int* edge_index = (const int*)d_in[12];
  float* out = (float*)d_out;

  char* ws = (char*)d_ws;
  unsigned short* y = (unsigned short*)ws;            //  3,200,000 B (bf16)
  float*  agg    = (float*)(ws + 3200000);            // 15,360,000 B
  int*    counts = (int*)(ws + 18560000);             // 80,000 B
  int*    ctr    = (int*)(ws + 18640000);             // 64 B
  int*    cursor = (int*)(ws + 18640064);             // 80,000 B
  u32x4*  meta   = (u32x4*)(ws + 18722048);           // 20,480,000 B (64-aligned)

  // zero counts + ctr (agg zeroed inside k_pre)
  hipError_t _e = hipMemsetAsync(counts, 0, 80064, stream); (void)_e;

  k_pre  <<<HIST_BLOCKS + YN_BLOCKS + AGGZ_BLOCKS, 256, 0, stream>>>(
            edge_index, counts, node_input, node_attr, W_l1_0, W_l1_1,
            y, (float4*)agg);
  k_alloc<<<(N_NODES+255)/256, 256, 0, stream>>>(counts, ctr, cursor);
  k_fill <<<(N_EDGES+255)/256, 256, 0, stream>>>(edge_index, edge_attr, edge_scalars,
                                                 cursor, meta);
  k_edge <<<768, 256, 0, stream>>>((const uint2*)meta, W_fc0, W_fc1, y, agg);
  k_finish<<<YN_BLOCKS, 256, 0, stream>>>(node_input, node_attr, W_sc0, W_sc1,
                                          W_l2_0, W_l2_1, agg, out);
}

// Round 14
// 311.408 us; speedup vs baseline: 1.0319x; 1.0319x over previous
//
#include <hip/hip_runtime.h>

#define N_NODES 20000
#define N_EDGES 640000
#define N_MT (N_EDGES/16)   // 40000 microtiles of 16 edges

typedef short short8 __attribute__((ext_vector_type(8)));
typedef float f32x4 __attribute__((ext_vector_type(4)));
typedef unsigned int u32x4 __attribute__((ext_vector_type(4)));

// RNE float -> bf16 bits
__device__ __forceinline__ unsigned int f2bf(float x){
  unsigned int u = __builtin_bit_cast(unsigned int, x);
  u += 0x7fffu + ((u >> 16) & 1u);
  return u >> 16;
}
__device__ __forceinline__ float bf2f(unsigned short u){
  unsigned int v = ((unsigned int)u) << 16;
  return __builtin_bit_cast(float, v);
}

__device__ __forceinline__ void wave_lds_fence(){
  __asm__ volatile("s_waitcnt lgkmcnt(0)" ::: "memory");
}
__device__ __forceinline__ void wave_vm_fence(){
  __asm__ volatile("s_waitcnt vmcnt(0)" ::: "memory");
}

// async global->LDS, 16B per lane; LDS dest = uniform base + laneId*16
__device__ __forceinline__ void gload16(const void* g, void* l){
  __builtin_amdgcn_global_load_lds(
      (const __attribute__((address_space(1))) unsigned int*)g,
      (__attribute__((address_space(3))) unsigned int*)l,
      16, 0, 0);
}

#define HIST_BLOCKS 625                    // 4 edges/thread, int4 loads
#define YN_BLOCKS   (N_NODES/16)           // 1250 (16 nodes per block)
#define AGGZ_BLOCKS 938                    // zero 3,840,000 floats, 16/thread

// ---- fused: edge-dst histogram + y = l1 linear (bf16 out) + agg zeroing ----
__global__ void k_pre(const int* __restrict__ ei, int* __restrict__ counts,
                      const float* __restrict__ ni, const float* __restrict__ na,
                      const float* __restrict__ Wl10, const float* __restrict__ Wl11,
                      unsigned short* __restrict__ y, float4* __restrict__ aggz){
  if (blockIdx.x < HIST_BLOCKS){
    int i = blockIdx.x*256 + threadIdx.x;
    if (i < N_EDGES/4){
      int4 d4 = *(const int4*)(ei + N_EDGES + i*4);
      atomicAdd(&counts[d4.x], 1);
      atomicAdd(&counts[d4.y], 1);
      atomicAdd(&counts[d4.z], 1);
      atomicAdd(&counts[d4.w], 1);
    }
    return;
  }
  if (blockIdx.x >= HIST_BLOCKS + YN_BLOCKS){
    int i = (blockIdx.x - HIST_BLOCKS - YN_BLOCKS)*256 + threadIdx.x;
    if (i < 240000){
      float4 z = {0.f,0.f,0.f,0.f};
      float4* p = aggz + (size_t)i*4;
      p[0]=z; p[1]=z; p[2]=z; p[3]=z;
    }
    return;
  }
  __shared__ float sW0[1024];
  __shared__ float sW1[256];
  __shared__ float sni[16*84];
  __shared__ float sna[16];
  const int t = threadIdx.x;
  const int nb = (blockIdx.x - HIST_BLOCKS)*16;
  for (int i=t; i<1024; i+=256) sW0[i] = Wl10[i];
  if (t < 256) sW1[t] = Wl11[t];
  for (int i=t; i<320; i+=256){
    int n = i/20, q = i - n*20;
    *(float4*)&sni[n*84 + q*4] = *(const float4*)(ni + (size_t)(nb+n)*80 + q*4);
  }
  if (t < 16) sna[t] = na[nb + t];
  __syncthreads();
  for (int i=t; i<1280; i+=256){
    int n = i/80, k = i - n*80;
    const float* row = sni + n*84;
    float a = sna[n];
    float acc = 0.f;
    if (k < 32){
      #pragma unroll
      for (int u=0; u<32; ++u) acc += row[u]*sW0[u*32+k];
      y[(size_t)nb*80 + i] = (unsigned short)f2bf(acc * a * 0.17677669529663687f);
    } else {
      int kk = k-32, v = kk/3, ii = kk - v*3;
      #pragma unroll
      for (int u=0; u<16; ++u) acc += row[32+u*3+ii]*sW1[u*16+v];
      y[(size_t)nb*80 + i] = (unsigned short)f2bf(acc * a * 0.25f);
    }
  }
}

// block-level base allocation (one atomic per 256 nodes)
__global__ void k_alloc(const int* __restrict__ counts, int* __restrict__ ctr,
                        int* __restrict__ cursor){
  __shared__ int wsum[4];
  __shared__ int s_base;
  const int t = threadIdx.x;
  const int lane = t & 63, wv = t >> 6;
  const int n = blockIdx.x*256 + t;
  int v = (n < N_NODES) ? counts[n] : 0;
  int x = v;
  #pragma unroll
  for (int off=1; off<64; off<<=1){
    int sh = __shfl_up(x, off, 64);
    if (lane >= off) x += sh;
  }
  if (lane == 63) wsum[wv] = x;
  __syncthreads();
  if (t == 0){
    int s0 = wsum[0], s1 = wsum[1], s2 = wsum[2], s3 = wsum[3];
    int total = s0 + s1 + s2 + s3;
    wsum[0] = 0; wsum[1] = s0; wsum[2] = s0+s1; wsum[3] = s0+s1+s2;
    s_base = atomicAdd(ctr, total);
  }
  __syncthreads();
  if (n < N_NODES) cursor[n] = s_base + wsum[wv] + (x - v);
}

// One 32B record per edge at its sorted position (u16 view):
// [0..9]=es bf16, [10..13]=ea bf16, [14..15]=u32 (src<<16|dst)
// r17: float2/float4 vectorized source loads; PLAIN meta stores (nt stores
// evict meta from L2/L3 -> k_edge +21us; nt is a dead branch, r15/r16).
__global__ void k_fill(const int* __restrict__ ei, const float* __restrict__ ea,
                       const float* __restrict__ es, int* __restrict__ cursor,
                       u32x4* __restrict__ meta){
  int e = blockIdx.x*256 + threadIdx.x;
  if (e >= N_EDGES) return;
  int s = ei[e], d = ei[N_EDGES + e];
  int pos = atomicAdd(&cursor[d], 1);
  const float4 eav = *(const float4*)(ea + (size_t)e*4);
  const float2* esp2 = (const float2*)(es + (size_t)e*10);
  float2 f0 = esp2[0], f1 = esp2[1], f2 = esp2[2], f3 = esp2[3], f4 = esp2[4];
  u32x4 m0, m1;
  m0[0] = f2bf(f0.x) | (f2bf(f0.y)<<16);
  m0[1] = f2bf(f1.x) | (f2bf(f1.y)<<16);
  m0[2] = f2bf(f2.x) | (f2bf(f2.y)<<16);
  m0[3] = f2bf(f3.x) | (f2bf(f3.y)<<16);
  m1[0] = f2bf(f4.x) | (f2bf(f4.y)<<16);
  m1[1] = f2bf(eav.x) | (f2bf(eav.y)<<16);
  m1[2] = f2bf(eav.z) | (f2bf(eav.w)<<16);
  m1[3] = ((unsigned int)s << 16) | (unsigned int)d;
  u32x4* mp = meta + (size_t)pos*2;
  mp[0] = m0;
  mp[1] = m1;
}

// ---------------- fused edge MLP + messages + segment-sum ----------------
// r0 pipeline + r19 transposed s_w + r20 tail-readlane + r21 two-pass
// e-loop. r24: REVERT r23's inline-asm v_cvt_pk_bf16_f32 (107.5->116.6,
// VALUBusy 67.7->72.9 -- asm blobs pin operands, add v_movs, and fragment
// compiler scheduling; matches learn_hip m240 "don't hand-write cvt_pk").
// Software f2bf restored. This source is the session-best structure.
// Ledger:
//  - transposed s_w (r19): 116->113, conflicts 2.96M->1.04M. CONFIRMED.
//  - tail-readlane (r20): total 319->314.7, conflicts ->560K. CONFIRMED.
//  - two-pass e-loop (r21): profiled k_edge ->107.5 full-clock,
//    VALUBusy ->67.7; total neutral. KEPT (kernel-level win).
//  - inline-asm cvt_pk (r23): 107.5->116.6. DEAD (check catalog nulls!).
//  - deferred atomic flush (r18): 116->119. vmcnt(0) NOT ack-stalled. DEAD.
//  - nt meta stores upstream: 117->138 (meta must stay L2-resident). DEAD.
//  - deep meta rotation + vmcnt(1) + sched_barrier(0): ->151. DEAD.
//  - DO NOT exec-mask global_load_lds (r11/r13: 117->164us).
//  - grid must stay 768 (3 blocks/CU; 1024 runs as two phases).
//  - NO waves-per-EU hint (r9/r10: VGPR squeeze -> scratch spills).
__global__ __launch_bounds__(256) void k_edge(
    const uint2* __restrict__ meta,
    const float* __restrict__ Wfc0, const float* __restrict__ Wfc1,
    const unsigned short* __restrict__ yb, float* __restrict__ agg){
  __shared__ float s_wfc0[640];                            // [k=10][n=64] f32
  __shared__ __align__(16) unsigned short s_w[4][96*20];   // per-wave [o][e] bf16, stride 20
  __shared__ __align__(16) unsigned short s_y[4][2][16*96];// dbuf y rows, stride 96 u16 (192B=12 chunks)
  __shared__ __align__(16) unsigned int  s_m[4][2][16*8];  // dbuf raw 32B records

  const int t = threadIdx.x;
  const int w = t >> 6, l = t & 63;
  const int r = l & 15, part = l >> 4;

  for (int i = t; i < 640; i += 256) s_wfc0[i] = Wfc0[i];

  // B-fragments of Wfc1 (bf16) in registers
  short8 b0[6], b1[6];
  #pragma unroll
  for (int nt=0; nt<6; ++nt){
    #pragma unroll
    for (int j=0; j<8; ++j){
      b0[nt][j] = (short)f2bf(Wfc1[(     part*8+j)*96 + nt*16 + r]);
      b1[nt][j] = (short)f2bf(Wfc1[(32 + part*8+j)*96 + nt*16 + r]);
    }
  }
  __syncthreads();   // only block barrier: s_wfc0 ready

  // per-lane message-channel constants
  int o_c[3], yo[3], eai[3];
  #pragma unroll
  for (int p=0; p<3; ++p){
    int c = p*64 + l;
    if (c < 32)      { o_c[p]=c;    yo[p]=c;        eai[p]=0; }
    else if (c < 48) { int u=c-32;  o_c[p]=80+u;    yo[p]=32+3*u; eai[p]=0; }
    else if (c < 144){ int idx=c-48;  int u=idx/3, fi=idx-u*3; o_c[p]=32+u; yo[p]=u;        eai[p]=1+fi; }
    else             { int idx=c-144; int u=idx/3, i =idx-u*3; o_c[p]=64+u; yo[p]=32+3*u+i; eai[p]=0; }
  }
  const bool dot0 = (l >= 32) && (l < 48);
  // ea shift-select precompute: word = eai>>1 (0:ea01,1:ea23), shamt=(eai&1)*16
  unsigned sh_[3]; bool whi_[3];
  #pragma unroll
  for (int p=0; p<3; ++p){ sh_[p] = (unsigned)((eai[p]&1)*16); whi_[p] = (eai[p]>>1)!=0; }

  unsigned short* sw = s_w[w];

  // y chunk assignment: instr i, lane l -> chunk idx=i*64+l; row=idx/12,
  // chunk-in-row byte offset = (idx%12)*16 (rows padded 160B->192B)
  int row_i[3], cir_i[3];
  #pragma unroll
  for (int i=0; i<3; ++i){
    int idx = i*64 + l;
    row_i[i] = idx/12;
    cir_i[i] = (idx - 12*row_i[i])*16;
  }

  const int gw = blockIdx.x*4 + w;
  const int nw = gridDim.x*4;
  const int m0 = (int)(((long long)gw     * N_MT) / nw);
  const int m1 = (int)(((long long)(gw+1) * N_MT) / nw);
  if (m0 >= m1) return;

  // ---- prologue: stage tile m0 into buffer 0
  uint2 mreg = meta[(size_t)m0*64 + l];
  {
    unsigned short* syn = s_y[w][0];
    #pragma unroll
    for (int i=0; i<3; ++i){
      int pk = __shfl((int)mreg.y, 4*row_i[i] + 3);
      unsigned src = ((unsigned)pk) >> 16;
      gload16((const char*)yb + (size_t)src*160 + cir_i[i], (char*)syn + i*1024);
    }
    *(uint2*)(&s_m[w][0][(l>>2)*8 + (l&3)*2]) = mreg;
  }
  mreg = meta[(size_t)((m0+1 < m1) ? m0+1 : m1-1)*64 + l];

  float acc0 = 0.f, acc1 = 0.f, acc2 = 0.f;
  int dcur = -1;
  int b = 0;

  for (int m = m0; m < m1; ++m){
    // ---- y(m) landed in s_y[b]; mreg = meta(m+1) ready
    wave_vm_fence();
    const int nb2 = b ^ 1;
    // ---- issue tile m+1 staging (DMA y -> s_y[nb2], raw meta -> s_m[nb2])
    {
      unsigned short* syn = s_y[w][nb2];
      #pragma unroll
      for (int i=0; i<3; ++i){
        int pk = __shfl((int)mreg.y, 4*row_i[i] + 3);
        unsigned src = ((unsigned)pk) >> 16;
        gload16((const char*)yb + (size_t)src*160 + cir_i[i], (char*)syn + i*1024);
      }
      *(uint2*)(&s_m[w][nb2][(l>>2)*8 + (l&3)*2]) = mreg;
    }
    // ---- prefetch meta(m+2)
    {
      int mnx = (m+2 < m1) ? m+2 : m1-1;
      mreg = meta[(size_t)mnx*64 + l];
    }
    wave_lds_fence();   // s_m writes visible (covers prologue on first iter)

    const unsigned int* smu = s_m[w][b];
    const unsigned short* syb = s_y[w][b];

    // ---- per-lane tail preload: edge (l&15) words 4..7 (16B aligned)
    u32x4 tail = *(const u32x4*)(smu + (l&15)*8 + 4);

    // ---- layer1: h[r][part*8+j] from raw record es (bf16)
    const unsigned short* esr = (const unsigned short*)(smu + r*8);
    float hv0[8], hv1[8];
    #pragma unroll
    for (int j=0; j<8; ++j){ hv0[j]=0.f; hv1[j]=0.f; }
    #pragma unroll
    for (int k=0; k<10; ++k){
      float ev = bf2f(esr[k]);
      const float* wr = s_wfc0 + k*64 + part*8;
      #pragma unroll
      for (int j=0; j<8; ++j){ hv0[j] += ev*wr[j]; hv1[j] += ev*wr[32+j]; }
    }
    short8 a0, a1;
    #pragma unroll
    for (int j=0; j<8; ++j){
      float x0 = hv0[j]*0.31622776601683794f;   // /sqrt(10)
      float x1 = hv1[j]*0.31622776601683794f;
      a0[j] = (short)f2bf(x0/(1.f+__expf(-x0)));
      a1[j] = (short)f2bf(x1/(1.f+__expf(-x1)));
    }

    // ---- layer2 MFMA: transposed store w[o=nt*16+r][e=part*4+rr]
    #pragma unroll
    for (int nt=0; nt<6; ++nt){
      f32x4 acc = {0.f,0.f,0.f,0.f};
      acc = __builtin_amdgcn_mfma_f32_16x16x32_bf16(a0, b0[nt], acc, 0,0,0);
      acc = __builtin_amdgcn_mfma_f32_16x16x32_bf16(a1, b1[nt], acc, 0,0,0);
      uint2 pkd;
      pkd.x = f2bf(acc[0]*0.125f) | (f2bf(acc[1]*0.125f)<<16);
      pkd.y = f2bf(acc[2]*0.125f) | (f2bf(acc[3]*0.125f)<<16);
      *(uint2*)(&sw[(nt*16+r)*20 + part*4]) = pkd;
    }
    wave_lds_fence();   // s_w visible

    // ---- preload this lane's 3 w-channel rows into registers
    unsigned int wr0[8], wr1[8], wr2[8];
    {
      const uint2* q0 = (const uint2*)(sw + o_c[0]*20);
      const uint2* q1 = (const uint2*)(sw + o_c[1]*20);
      const uint2* q2 = (const uint2*)(sw + o_c[2]*20);
      uint2 a, bb, c, d;
      a=q0[0]; bb=q0[1]; c=q0[2]; d=q0[3];
      wr0[0]=a.x; wr0[1]=a.y; wr0[2]=bb.x; wr0[3]=bb.y;
      wr0[4]=c.x; wr0[5]=c.y; wr0[6]=d.x; wr0[7]=d.y;
      a=q1[0]; bb=q1[1]; c=q1[2]; d=q1[3];
      wr1[0]=a.x; wr1[1]=a.y; wr1[2]=bb.x; wr1[3]=bb.y;
      wr1[4]=c.x; wr1[5]=c.y; wr1[6]=d.x; wr1[7]=d.y;
      a=q2[0]; bb=q2[1]; c=q2[2]; d=q2[3];
      wr2[0]=a.x; wr2[1]=a.y; wr2[2]=bb.x; wr2[3]=bb.y;
      wr2[4]=c.x; wr2[5]=c.y; wr2[6]=d.x; wr2[7]=d.y;
    }

    // ---- pass 1: branch-free per-edge messages into registers.
    // 48 y-reads share 3 base addrs + imm offsets -> burst-issue.
    float msg0[16], msg1[16], msg2[16];
    #pragma unroll
    for (int e=0; e<16; ++e){
      unsigned ea01 = (unsigned)__builtin_amdgcn_readlane((int)tail[1], e);
      unsigned ea23 = (unsigned)__builtin_amdgcn_readlane((int)tail[2], e);
      const unsigned short* sye = syb + e*96;
      float wv0 = bf2f((e&1) ? (unsigned short)(wr0[e>>1]>>16) : (unsigned short)wr0[e>>1]);
      float wv1 = bf2f((e&1) ? (unsigned short)(wr1[e>>1]>>16) : (unsigned short)wr1[e>>1]);
      float wv2 = bf2f((e&1) ? (unsigned short)(wr2[e>>1]>>16) : (unsigned short)wr2[e>>1]);
      unsigned ew0 = whi_[0] ? ea23 : ea01;
      unsigned ew1 = whi_[1] ? ea23 : ea01;
      unsigned ew2 = whi_[2] ? ea23 : ea01;
      float ea0f = __builtin_bit_cast(float, (ew0 >> sh_[0]) << 16);
      float ea1f = __builtin_bit_cast(float, (ew1 >> sh_[1]) << 16);
      float ea2f = __builtin_bit_cast(float, (ew2 >> sh_[2]) << 16);
      float m0v;
      if (dot0){
        float e1f = __builtin_bit_cast(float, ea01 & 0xffff0000u);
        float e2f = __builtin_bit_cast(float, ea23 << 16);
        float e3f = __builtin_bit_cast(float, ea23 & 0xffff0000u);
        m0v = wv0 *
              (bf2f(sye[yo[0]])*e1f + bf2f(sye[yo[0]+1])*e2f
               + bf2f(sye[yo[0]+2])*e3f)
              * 0.5773502691896258f;   // /sqrt(3)
      } else {
        m0v = wv0 * bf2f(sye[yo[0]]) * ea0f;
      }
      msg0[e] = m0v;
      msg1[e] = wv1 * bf2f(sye[yo[1]]) * ea1f;
      msg2[e] = wv2 * bf2f(sye[yo[2]]) * ea2f;
    }

    // ---- pass 2: LDS-free segment-sum (scalar branch, register adds)
    #pragma unroll
    for (int e=0; e<16; ++e){
      unsigned sdw = (unsigned)__builtin_amdgcn_readlane((int)tail[3], e);
      int de = (int)(sdw & 0xffffu);
      if (de != dcur){
        if (dcur >= 0){
          unsafeAtomicAdd(&agg[(size_t)dcur*192 +       l], acc0);
          unsafeAtomicAdd(&agg[(size_t)dcur*192 +  64 + l], acc1);
          unsafeAtomicAdd(&agg[(size_t)dcur*192 + 128 + l], acc2);
        }
        acc0 = acc1 = acc2 = 0.f;
        dcur = de;
      }
      acc0 += msg0[e];
      acc1 += msg1[e];
      acc2 += msg2[e];
    }

    b = nb2;
  }
  if (dcur >= 0){
    unsafeAtomicAdd(&agg[(size_t)dcur*192 +       l], acc0);
    unsafeAtomicAdd(&agg[(size_t)dcur*192 +  64 + l], acc1);
    unsafeAtomicAdd(&agg[(size_t)dcur*192 + 128 + l], acc2);
  }
}

// ---------------- finish: z = agg @ W_l2, out = c_s*s + c_x*z ----------------
__global__ void k_finish(const float* __restrict__ ni, const float* __restrict__ na,
    const float* __restrict__ Wsc0, const float* __restrict__ Wsc1,
    const float* __restrict__ Wl20, const float* __restrict__ Wl21,
    const float* __restrict__ agg, float* __restrict__ out){
  __shared__ float sWsc0[1024];
  __shared__ float sWsc1[256];
  __shared__ float sWl20[1536];
  __shared__ float sWl21[768];
  __shared__ float sni[16*84];
  __shared__ float sag[16*196];
  __shared__ float sna[16];
  const int t = threadIdx.x;
  const int nb = blockIdx.x*16;
  for (int i=t; i<1024; i+=256) sWsc0[i] = Wsc0[i];
  if (t < 256) sWsc1[t] = Wsc1[t];
  for (int i=t; i<1536; i+=256) sWl20[i] = Wl20[i];
  for (int i=t; i<768;  i+=256) sWl21[i] = Wl21[i];
  for (int i=t; i<320;  i+=256){
    int n = i/20, q = i - n*20;
    *(float4*)&sni[n*84 + q*4] = *(const float4*)(ni + (size_t)(nb+n)*80 + q*4);
  }
  for (int i=t; i<768;  i+=256){
    int n = i/48, q = i - n*48;
    *(float4*)&sag[n*196 + q*4] = *(const float4*)(agg + (size_t)(nb+n)*192 + q*4);
  }
  if (t < 16) sna[t] = na[nb + t];
  __syncthreads();

  const float c_s = 0.3826834323650898f;   // sin(pi/8)
  const float c_x = 0.9238795325112867f;   // cos(pi/8)
  const float zscale = 0.17677669529663687f * 0.14433756729740643f;
  for (int i=t; i<1280; i+=256){
    int n = i/80, k = i - n*80;
    const float* row = sni + n*84;
    const float* ag  = sag + n*196;
    float a = sna[n];
    float s = 0.f, z = 0.f;
    if (k < 32){
      #pragma unroll
      for (int u=0; u<32; ++u) s += row[u]*sWsc0[u*32+k];
      s *= a * 0.17677669529663687f;
      #pragma unroll
      for (int u=0; u<48; ++u) z += ag[u]*sWl20[u*32+k];
    } else {
      int kk=k-32, v=kk/3, ii=kk-v*3;
      #pragma unroll
      for (int u=0; u<16; ++u) s += row[32+u*3+ii]*sWsc1[u*16+v];
      s *= a * 0.25f;
      #pragma unroll
      for (int u=0; u<48; ++u) z += ag[48+u*3+ii]*sWl21[u*16+v];
    }
    out[(size_t)nb*80 + i] = c_s*s + c_x*z*zscale;
  }
}

extern "C" void kernel_launch(void* const* d_in, const int* in_sizes, int n_in,
                              void* d_out, int out_size, void* d_ws, size_t ws_size,
                              hipStream_t stream){
  const float* node_input   = (const float*)d_in[0];
  const float* node_attr    = (const float*)d_in[1];
  const float* edge_attr    = (const float*)d_in[2];
  const float* edge_scalars = (const float*)d_in[3];
  const float* W_sc0 = (const float*)d_in[4];
  const float* W_sc1 = (const float*)d_in[5];
  const float* W_l1_0 = (const float*)d_in[6];
  const float* W_l1_1 = (const float*)d_in[7];
  const float* W_fc0 = (const float*)d_in[8];
  const float* W_fc1 = (const float*)d_in[9];
  const float* W_l2_0 = (const float*)d_in[10];
  const float* W_l2_1 = (const float*)d_in[11];
  const int* edge_index = (const int*)d_in[12];
  float* out = (float*)d_out;

  char* ws = (char*)d_ws;
  unsigned short* y = (unsigned short*)ws;            //  3,200,000 B (bf16)
  float*  agg    = (float*)(ws + 3200000);            // 15,360,000 B
  int*    counts = (int*)(ws + 18560000);             // 80,000 B
  int*    ctr    = (int*)(ws + 18640000);             // 64 B
  int*    cursor = (int*)(ws + 18640064);             // 80,000 B
  u32x4*  meta   = (u32x4*)(ws + 18722048);           // 20,480,000 B (64-aligned)

  // zero counts + ctr (agg zeroed inside k_pre)
  hipError_t _e = hipMemsetAsync(counts, 0, 80064, stream); (void)_e;

  k_pre  <<<HIST_BLOCKS + YN_BLOCKS + AGGZ_BLOCKS, 256, 0, stream>>>(
            edge_index, counts, node_input, node_attr, W_l1_0, W_l1_1,
            y, (float4*)agg);
  k_alloc<<<(N_NODES+255)/256, 256, 0, stream>>>(counts, ctr, cursor);
  k_fill <<<(N_EDGES+255)/256, 256, 0, stream>>>(edge_index, edge_attr, edge_scalars,
                                                 cursor, meta);
  k_edge <<<768, 256, 0, stream>>>((const uint2*)meta, W_fc0, W_fc1, y, agg);
  k_finish<<<YN_BLOCKS, 256, 0, stream>>>(node_input, node_attr, W_sc0, W_sc1,
                                          W_l2_0, W_l2_1, agg, out);
}

// Round 15
// 310.832 us; speedup vs baseline: 1.0338x; 1.0019x over previous
//
#include <hip/hip_runtime.h>

#define N_NODES 20000
#define N_EDGES 640000
#define N_MT (N_EDGES/16)   // 40000 microtiles of 16 edges

typedef short short8 __attribute__((ext_vector_type(8)));
typedef float f32x4 __attribute__((ext_vector_type(4)));
typedef unsigned int u32x4 __attribute__((ext_vector_type(4)));

// RNE float -> bf16 bits
__device__ __forceinline__ unsigned int f2bf(float x){
  unsigned int u = __builtin_bit_cast(unsigned int, x);
  u += 0x7fffu + ((u >> 16) & 1u);
  return u >> 16;
}
__device__ __forceinline__ float bf2f(unsigned short u){
  unsigned int v = ((unsigned int)u) << 16;
  return __builtin_bit_cast(float, v);
}

__device__ __forceinline__ void wave_lds_fence(){
  __asm__ volatile("s_waitcnt lgkmcnt(0)" ::: "memory");
}
__device__ __forceinline__ void wave_vm_fence(){
  __asm__ volatile("s_waitcnt vmcnt(0)" ::: "memory");
}

// async global->LDS, 16B per lane; LDS dest = uniform base + laneId*16
__device__ __forceinline__ void gload16(const void* g, void* l){
  __builtin_amdgcn_global_load_lds(
      (const __attribute__((address_space(1))) unsigned int*)g,
      (__attribute__((address_space(3))) unsigned int*)l,
      16, 0, 0);
}

#define HIST_BLOCKS 625                    // 4 edges/thread, int4 loads
#define YN_BLOCKS   (N_NODES/16)           // 1250 (16 nodes per block)
#define AGGZ_BLOCKS 938                    // zero 3,840,000 floats, 16/thread

// ---- fused: edge-dst histogram + y = l1 linear (bf16 out) + agg zeroing ----
__global__ void k_pre(const int* __restrict__ ei, int* __restrict__ counts,
                      const float* __restrict__ ni, const float* __restrict__ na,
                      const float* __restrict__ Wl10, const float* __restrict__ Wl11,
                      unsigned short* __restrict__ y, float4* __restrict__ aggz){
  if (blockIdx.x < HIST_BLOCKS){
    int i = blockIdx.x*256 + threadIdx.x;
    if (i < N_EDGES/4){
      int4 d4 = *(const int4*)(ei + N_EDGES + i*4);
      atomicAdd(&counts[d4.x], 1);
      atomicAdd(&counts[d4.y], 1);
      atomicAdd(&counts[d4.z], 1);
      atomicAdd(&counts[d4.w], 1);
    }
    return;
  }
  if (blockIdx.x >= HIST_BLOCKS + YN_BLOCKS){
    int i = (blockIdx.x - HIST_BLOCKS - YN_BLOCKS)*256 + threadIdx.x;
    if (i < 240000){
      float4 z = {0.f,0.f,0.f,0.f};
      float4* p = aggz + (size_t)i*4;
      p[0]=z; p[1]=z; p[2]=z; p[3]=z;
    }
    return;
  }
  __shared__ float sW0[1024];
  __shared__ float sW1[256];
  __shared__ float sni[16*84];
  __shared__ float sna[16];
  const int t = threadIdx.x;
  const int nb = (blockIdx.x - HIST_BLOCKS)*16;
  for (int i=t; i<1024; i+=256) sW0[i] = Wl10[i];
  if (t < 256) sW1[t] = Wl11[t];
  for (int i=t; i<320; i+=256){
    int n = i/20, q = i - n*20;
    *(float4*)&sni[n*84 + q*4] = *(const float4*)(ni + (size_t)(nb+n)*80 + q*4);
  }
  if (t < 16) sna[t] = na[nb + t];
  __syncthreads();
  for (int i=t; i<1280; i+=256){
    int n = i/80, k = i - n*80;
    const float* row = sni + n*84;
    float a = sna[n];
    float acc = 0.f;
    if (k < 32){
      #pragma unroll
      for (int u=0; u<32; ++u) acc += row[u]*sW0[u*32+k];
      y[(size_t)nb*80 + i] = (unsigned short)f2bf(acc * a * 0.17677669529663687f);
    } else {
      int kk = k-32, v = kk/3, ii = kk - v*3;
      #pragma unroll
      for (int u=0; u<16; ++u) acc += row[32+u*3+ii]*sW1[u*16+v];
      y[(size_t)nb*80 + i] = (unsigned short)f2bf(acc * a * 0.25f);
    }
  }
}

// block-level base allocation (one atomic per 256 nodes)
__global__ void k_alloc(const int* __restrict__ counts, int* __restrict__ ctr,
                        int* __restrict__ cursor){
  __shared__ int wsum[4];
  __shared__ int s_base;
  const int t = threadIdx.x;
  const int lane = t & 63, wv = t >> 6;
  const int n = blockIdx.x*256 + t;
  int v = (n < N_NODES) ? counts[n] : 0;
  int x = v;
  #pragma unroll
  for (int off=1; off<64; off<<=1){
    int sh = __shfl_up(x, off, 64);
    if (lane >= off) x += sh;
  }
  if (lane == 63) wsum[wv] = x;
  __syncthreads();
  if (t == 0){
    int s0 = wsum[0], s1 = wsum[1], s2 = wsum[2], s3 = wsum[3];
    int total = s0 + s1 + s2 + s3;
    wsum[0] = 0; wsum[1] = s0; wsum[2] = s0+s1; wsum[3] = s0+s1+s2;
    s_base = atomicAdd(ctr, total);
  }
  __syncthreads();
  if (n < N_NODES) cursor[n] = s_base + wsum[wv] + (x - v);
}

// One 32B record per edge at its sorted position (u16 view):
// [0..9]=es bf16, [10..13]=ea bf16, [14..15]=u32 (src<<16|dst)
// r17: float2/float4 vectorized source loads; PLAIN meta stores.
// NOTE (r25 ledger correction): r15's "nt stores save 19us in k_fill"
// was a clock-skewed-profile artifact (hbm_gbps 311 vs 370 at identical
// FETCH — same replay-DVFS signature as r21's 135us anomaly). Timed
// totals put nt within noise; plain stores kept for simplicity.
__global__ void k_fill(const int* __restrict__ ei, const float* __restrict__ ea,
                       const float* __restrict__ es, int* __restrict__ cursor,
                       u32x4* __restrict__ meta){
  int e = blockIdx.x*256 + threadIdx.x;
  if (e >= N_EDGES) return;
  int s = ei[e], d = ei[N_EDGES + e];
  int pos = atomicAdd(&cursor[d], 1);
  const float4 eav = *(const float4*)(ea + (size_t)e*4);
  const float2* esp2 = (const float2*)(es + (size_t)e*10);
  float2 f0 = esp2[0], f1 = esp2[1], f2 = esp2[2], f3 = esp2[3], f4 = esp2[4];
  u32x4 m0, m1;
  m0[0] = f2bf(f0.x) | (f2bf(f0.y)<<16);
  m0[1] = f2bf(f1.x) | (f2bf(f1.y)<<16);
  m0[2] = f2bf(f2.x) | (f2bf(f2.y)<<16);
  m0[3] = f2bf(f3.x) | (f2bf(f3.y)<<16);
  m1[0] = f2bf(f4.x) | (f2bf(f4.y)<<16);
  m1[1] = f2bf(eav.x) | (f2bf(eav.y)<<16);
  m1[2] = f2bf(eav.z) | (f2bf(eav.w)<<16);
  m1[3] = ((unsigned int)s << 16) | (unsigned int)d;
  u32x4* mp = meta + (size_t)pos*2;
  mp[0] = m0;
  mp[1] = m1;
}

// ---------------- fused edge MLP + messages + segment-sum ----------------
// FINAL (session-converged): r0 dbuf DMA pipeline + r19 transposed s_w
// [o][e] stride-20 + r20 tail-readlane (dst/ea via v_readlane, scalar
// flush branch) + r21 two-pass e-loop (branch-free message pass, LDS-free
// segment-sum pass). k_edge 116.4 -> 107.5us, total 322 -> 311.4us.
// Convergence: VALUBusy 68% at LDS-pinned 3 blocks/CU; DMA-gather service
// latency is the residual and deeper pipelining failed twice (r16, r18);
// LDS cannot drop below ~40KB without breaking the stride-96 DMA layout
// (r11/r13) or s_w banking. Not a HW roofline (HBM 5%, MFMA 3%) — a
// structural floor for this decomposition.
// Ledger:
//  - transposed s_w (r19): 116->113, conflicts 2.96M->1.04M. CONFIRMED.
//  - tail-readlane (r20): total 319->314.7, conflicts ->560K. CONFIRMED.
//  - two-pass e-loop (r21): k_edge ->107.5, VALUBusy ->68. CONFIRMED.
//  - inline-asm cvt_pk (r23): 107.5->116.6. DEAD (catalog m240 said so).
//  - deferred atomic flush (r18): 116->119. DEAD.
//  - nt meta stores (r15): within noise on timed total (ledger corrected
//    r25 — original +21us k_edge reading was clock-skewed replay). DEAD.
//  - deep meta rotation + vmcnt(1) + sched_barrier(0) (r16): ->151. DEAD.
//  - DO NOT exec-mask global_load_lds (r11/r13: 117->164us).
//  - grid must stay 768 (3 blocks/CU; 1024 runs as two phases).
//  - NO waves-per-EU hint (r9/r10: VGPR squeeze -> scratch spills).
//  - profiling replays can run ~16% down-clocked: check hbm_gbps vs
//    FETCH before trusting profiled dur_us (r21/r25).
__global__ __launch_bounds__(256) void k_edge(
    const uint2* __restrict__ meta,
    const float* __restrict__ Wfc0, const float* __restrict__ Wfc1,
    const unsigned short* __restrict__ yb, float* __restrict__ agg){
  __shared__ float s_wfc0[640];                            // [k=10][n=64] f32
  __shared__ __align__(16) unsigned short s_w[4][96*20];   // per-wave [o][e] bf16, stride 20
  __shared__ __align__(16) unsigned short s_y[4][2][16*96];// dbuf y rows, stride 96 u16 (192B=12 chunks)
  __shared__ __align__(16) unsigned int  s_m[4][2][16*8];  // dbuf raw 32B records

  const int t = threadIdx.x;
  const int w = t >> 6, l = t & 63;
  const int r = l & 15, part = l >> 4;

  for (int i = t; i < 640; i += 256) s_wfc0[i] = Wfc0[i];

  // B-fragments of Wfc1 (bf16) in registers
  short8 b0[6], b1[6];
  #pragma unroll
  for (int nt=0; nt<6; ++nt){
    #pragma unroll
    for (int j=0; j<8; ++j){
      b0[nt][j] = (short)f2bf(Wfc1[(     part*8+j)*96 + nt*16 + r]);
      b1[nt][j] = (short)f2bf(Wfc1[(32 + part*8+j)*96 + nt*16 + r]);
    }
  }
  __syncthreads();   // only block barrier: s_wfc0 ready

  // per-lane message-channel constants
  int o_c[3], yo[3], eai[3];
  #pragma unroll
  for (int p=0; p<3; ++p){
    int c = p*64 + l;
    if (c < 32)      { o_c[p]=c;    yo[p]=c;        eai[p]=0; }
    else if (c < 48) { int u=c-32;  o_c[p]=80+u;    yo[p]=32+3*u; eai[p]=0; }
    else if (c < 144){ int idx=c-48;  int u=idx/3, fi=idx-u*3; o_c[p]=32+u; yo[p]=u;        eai[p]=1+fi; }
    else             { int idx=c-144; int u=idx/3, i =idx-u*3; o_c[p]=64+u; yo[p]=32+3*u+i; eai[p]=0; }
  }
  const bool dot0 = (l >= 32) && (l < 48);
  // ea shift-select precompute: word = eai>>1 (0:ea01,1:ea23), shamt=(eai&1)*16
  unsigned sh_[3]; bool whi_[3];
  #pragma unroll
  for (int p=0; p<3; ++p){ sh_[p] = (unsigned)((eai[p]&1)*16); whi_[p] = (eai[p]>>1)!=0; }

  unsigned short* sw = s_w[w];

  // y chunk assignment: instr i, lane l -> chunk idx=i*64+l; row=idx/12,
  // chunk-in-row byte offset = (idx%12)*16 (rows padded 160B->192B)
  int row_i[3], cir_i[3];
  #pragma unroll
  for (int i=0; i<3; ++i){
    int idx = i*64 + l;
    row_i[i] = idx/12;
    cir_i[i] = (idx - 12*row_i[i])*16;
  }

  const int gw = blockIdx.x*4 + w;
  const int nw = gridDim.x*4;
  const int m0 = (int)(((long long)gw     * N_MT) / nw);
  const int m1 = (int)(((long long)(gw+1) * N_MT) / nw);
  if (m0 >= m1) return;

  // ---- prologue: stage tile m0 into buffer 0
  uint2 mreg = meta[(size_t)m0*64 + l];
  {
    unsigned short* syn = s_y[w][0];
    #pragma unroll
    for (int i=0; i<3; ++i){
      int pk = __shfl((int)mreg.y, 4*row_i[i] + 3);
      unsigned src = ((unsigned)pk) >> 16;
      gload16((const char*)yb + (size_t)src*160 + cir_i[i], (char*)syn + i*1024);
    }
    *(uint2*)(&s_m[w][0][(l>>2)*8 + (l&3)*2]) = mreg;
  }
  mreg = meta[(size_t)((m0+1 < m1) ? m0+1 : m1-1)*64 + l];

  float acc0 = 0.f, acc1 = 0.f, acc2 = 0.f;
  int dcur = -1;
  int b = 0;

  for (int m = m0; m < m1; ++m){
    // ---- y(m) landed in s_y[b]; mreg = meta(m+1) ready
    wave_vm_fence();
    const int nb2 = b ^ 1;
    // ---- issue tile m+1 staging (DMA y -> s_y[nb2], raw meta -> s_m[nb2])
    {
      unsigned short* syn = s_y[w][nb2];
      #pragma unroll
      for (int i=0; i<3; ++i){
        int pk = __shfl((int)mreg.y, 4*row_i[i] + 3);
        unsigned src = ((unsigned)pk) >> 16;
        gload16((const char*)yb + (size_t)src*160 + cir_i[i], (char*)syn + i*1024);
      }
      *(uint2*)(&s_m[w][nb2][(l>>2)*8 + (l&3)*2]) = mreg;
    }
    // ---- prefetch meta(m+2)
    {
      int mnx = (m+2 < m1) ? m+2 : m1-1;
      mreg = meta[(size_t)mnx*64 + l];
    }
    wave_lds_fence();   // s_m writes visible (covers prologue on first iter)

    const unsigned int* smu = s_m[w][b];
    const unsigned short* syb = s_y[w][b];

    // ---- per-lane tail preload: edge (l&15) words 4..7 (16B aligned)
    u32x4 tail = *(const u32x4*)(smu + (l&15)*8 + 4);

    // ---- layer1: h[r][part*8+j] from raw record es (bf16)
    const unsigned short* esr = (const unsigned short*)(smu + r*8);
    float hv0[8], hv1[8];
    #pragma unroll
    for (int j=0; j<8; ++j){ hv0[j]=0.f; hv1[j]=0.f; }
    #pragma unroll
    for (int k=0; k<10; ++k){
      float ev = bf2f(esr[k]);
      const float* wr = s_wfc0 + k*64 + part*8;
      #pragma unroll
      for (int j=0; j<8; ++j){ hv0[j] += ev*wr[j]; hv1[j] += ev*wr[32+j]; }
    }
    short8 a0, a1;
    #pragma unroll
    for (int j=0; j<8; ++j){
      float x0 = hv0[j]*0.31622776601683794f;   // /sqrt(10)
      float x1 = hv1[j]*0.31622776601683794f;
      a0[j] = (short)f2bf(x0/(1.f+__expf(-x0)));
      a1[j] = (short)f2bf(x1/(1.f+__expf(-x1)));
    }

    // ---- layer2 MFMA: transposed store w[o=nt*16+r][e=part*4+rr]
    #pragma unroll
    for (int nt=0; nt<6; ++nt){
      f32x4 acc = {0.f,0.f,0.f,0.f};
      acc = __builtin_amdgcn_mfma_f32_16x16x32_bf16(a0, b0[nt], acc, 0,0,0);
      acc = __builtin_amdgcn_mfma_f32_16x16x32_bf16(a1, b1[nt], acc, 0,0,0);
      uint2 pkd;
      pkd.x = f2bf(acc[0]*0.125f) | (f2bf(acc[1]*0.125f)<<16);
      pkd.y = f2bf(acc[2]*0.125f) | (f2bf(acc[3]*0.125f)<<16);
      *(uint2*)(&sw[(nt*16+r)*20 + part*4]) = pkd;
    }
    wave_lds_fence();   // s_w visible

    // ---- preload this lane's 3 w-channel rows into registers
    unsigned int wr0[8], wr1[8], wr2[8];
    {
      const uint2* q0 = (const uint2*)(sw + o_c[0]*20);
      const uint2* q1 = (const uint2*)(sw + o_c[1]*20);
      const uint2* q2 = (const uint2*)(sw + o_c[2]*20);
      uint2 a, bb, c, d;
      a=q0[0]; bb=q0[1]; c=q0[2]; d=q0[3];
      wr0[0]=a.x; wr0[1]=a.y; wr0[2]=bb.x; wr0[3]=bb.y;
      wr0[4]=c.x; wr0[5]=c.y; wr0[6]=d.x; wr0[7]=d.y;
      a=q1[0]; bb=q1[1]; c=q1[2]; d=q1[3];
      wr1[0]=a.x; wr1[1]=a.y; wr1[2]=bb.x; wr1[3]=bb.y;
      wr1[4]=c.x; wr1[5]=c.y; wr1[6]=d.x; wr1[7]=d.y;
      a=q2[0]; bb=q2[1]; c=q2[2]; d=q2[3];
      wr2[0]=a.x; wr2[1]=a.y; wr2[2]=bb.x; wr2[3]=bb.y;
      wr2[4]=c.x; wr2[5]=c.y; wr2[6]=d.x; wr2[7]=d.y;
    }

    // ---- pass 1: branch-free per-edge messages into registers.
    // 48 y-reads share 3 base addrs + imm offsets -> burst-issue.
    float msg0[16], msg1[16], msg2[16];
    #pragma unroll
    for (int e=0; e<16; ++e){
      unsigned ea01 = (unsigned)__builtin_amdgcn_readlane((int)tail[1], e);
      unsigned ea23 = (unsigned)__builtin_amdgcn_readlane((int)tail[2], e);
      const unsigned short* sye = syb + e*96;
      float wv0 = bf2f((e&1) ? (unsigned short)(wr0[e>>1]>>16) : (unsigned short)wr0[e>>1]);
      float wv1 = bf2f((e&1) ? (unsigned short)(wr1[e>>1]>>16) : (unsigned short)wr1[e>>1]);
      float wv2 = bf2f((e&1) ? (unsigned short)(wr2[e>>1]>>16) : (unsigned short)wr2[e>>1]);
      unsigned ew0 = whi_[0] ? ea23 : ea01;
      unsigned ew1 = whi_[1] ? ea23 : ea01;
      unsigned ew2 = whi_[2] ? ea23 : ea01;
      float ea0f = __builtin_bit_cast(float, (ew0 >> sh_[0]) << 16);
      float ea1f = __builtin_bit_cast(float, (ew1 >> sh_[1]) << 16);
      float ea2f = __builtin_bit_cast(float, (ew2 >> sh_[2]) << 16);
      float m0v;
      if (dot0){
        float e1f = __builtin_bit_cast(float, ea01 & 0xffff0000u);
        float e2f = __builtin_bit_cast(float, ea23 << 16);
        float e3f = __builtin_bit_cast(float, ea23 & 0xffff0000u);
        m0v = wv0 *
              (bf2f(sye[yo[0]])*e1f + bf2f(sye[yo[0]+1])*e2f
               + bf2f(sye[yo[0]+2])*e3f)
              * 0.5773502691896258f;   // /sqrt(3)
      } else {
        m0v = wv0 * bf2f(sye[yo[0]]) * ea0f;
      }
      msg0[e] = m0v;
      msg1[e] = wv1 * bf2f(sye[yo[1]]) * ea1f;
      msg2[e] = wv2 * bf2f(sye[yo[2]]) * ea2f;
    }

    // ---- pass 2: LDS-free segment-sum (scalar branch, register adds)
    #pragma unroll
    for (int e=0; e<16; ++e){
      unsigned sdw = (unsigned)__builtin_amdgcn_readlane((int)tail[3], e);
      int de = (int)(sdw & 0xffffu);
      if (de != dcur){
        if (dcur >= 0){
          unsafeAtomicAdd(&agg[(size_t)dcur*192 +       l], acc0);
          unsafeAtomicAdd(&agg[(size_t)dcur*192 +  64 + l], acc1);
          unsafeAtomicAdd(&agg[(size_t)dcur*192 + 128 + l], acc2);
        }
        acc0 = acc1 = acc2 = 0.f;
        dcur = de;
      }
      acc0 += msg0[e];
      acc1 += msg1[e];
      acc2 += msg2[e];
    }

    b = nb2;
  }
  if (dcur >= 0){
    unsafeAtomicAdd(&agg[(size_t)dcur*192 +       l], acc0);
    unsafeAtomicAdd(&agg[(size_t)dcur*192 +  64 + l], acc1);
    unsafeAtomicAdd(&agg[(size_t)dcur*192 + 128 + l], acc2);
  }
}

// ---------------- finish: z = agg @ W_l2, out = c_s*s + c_x*z ----------------
__global__ void k_finish(const float* __restrict__ ni, const float* __restrict__ na,
    const float* __restrict__ Wsc0, const float* __restrict__ Wsc1,
    const float* __restrict__ Wl20, const float* __restrict__ Wl21,
    const float* __restrict__ agg, float* __restrict__ out){
  __shared__ float sWsc0[1024];
  __shared__ float sWsc1[256];
  __shared__ float sWl20[1536];
  __shared__ float sWl21[768];
  __shared__ float sni[16*84];
  __shared__ float sag[16*196];
  __shared__ float sna[16];
  const int t = threadIdx.x;
  const int nb = blockIdx.x*16;
  for (int i=t; i<1024; i+=256) sWsc0[i] = Wsc0[i];
  if (t < 256) sWsc1[t] = Wsc1[t];
  for (int i=t; i<1536; i+=256) sWl20[i] = Wl20[i];
  for (int i=t; i<768;  i+=256) sWl21[i] = Wl21[i];
  for (int i=t; i<320;  i+=256){
    int n = i/20, q = i - n*20;
    *(float4*)&sni[n*84 + q*4] = *(const float4*)(ni + (size_t)(nb+n)*80 + q*4);
  }
  for (int i=t; i<768;  i+=256){
    int n = i/48, q = i - n*48;
    *(float4*)&sag[n*196 + q*4] = *(const float4*)(agg + (size_t)(nb+n)*192 + q*4);
  }
  if (t < 16) sna[t] = na[nb + t];
  __syncthreads();

  const float c_s = 0.3826834323650898f;   // sin(pi/8)
  const float c_x = 0.9238795325112867f;   // cos(pi/8)
  const float zscale = 0.17677669529663687f * 0.14433756729740643f;
  for (int i=t; i<1280; i+=256){
    int n = i/80, k = i - n*80;
    const float* row = sni + n*84;
    const float* ag  = sag + n*196;
    float a = sna[n];
    float s = 0.f, z = 0.f;
    if (k < 32){
      #pragma unroll
      for (int u=0; u<32; ++u) s += row[u]*sWsc0[u*32+k];
      s *= a * 0.17677669529663687f;
      #pragma unroll
      for (int u=0; u<48; ++u) z += ag[u]*sWl20[u*32+k];
    } else {
      int kk=k-32, v=kk/3, ii=kk-v*3;
      #pragma unroll
      for (int u=0; u<16; ++u) s += row[32+u*3+ii]*sWsc1[u*16+v];
      s *= a * 0.25f;
      #pragma unroll
      for (int u=0; u<48; ++u) z += ag[48+u*3+ii]*sWl21[u*16+v];
    }
    out[(size_t)nb*80 + i] = c_s*s + c_x*z*zscale;
  }
}

extern "C" void kernel_launch(void* const* d_in, const int* in_sizes, int n_in,
                              void* d_out, int out_size, void* d_ws, size_t ws_size,
                              hipStream_t stream){
  const float* node_input   = (const float*)d_in[0];
  const float* node_attr    = (const float*)d_in[1];
  const float* edge_attr    = (const float*)d_in[2];
  const float* edge_scalars = (const float*)d_in[3];
  const float* W_sc0 = (const float*)d_in[4];
  const float* W_sc1 = (const float*)d_in[5];
  const float* W_l1_0 = (const float*)d_in[6];
  const float* W_l1_1 = (const float*)d_in[7];
  const float* W_fc0 = (const float*)d_in[8];
  const float* W_fc1 = (const float*)d_in[9];
  const float* W_l2_0 = (const float*)d_in[10];
  const float* W_l2_1 = (const float*)d_in[11];
  const int* edge_index = (const int*)d_in[12];
  float* out = (float*)d_out;

  char* ws = (char*)d_ws;
  unsigned short* y = (unsigned short*)ws;            //  3,200,000 B (bf16)
  float*  agg    = (float*)(ws + 3200000);            // 15,360,000 B
  int*    counts = (int*)(ws + 18560000);             // 80,000 B
  int*    ctr    = (int*)(ws + 18640000);             // 64 B
  int*    cursor = (int*)(ws + 18640064);             // 80,000 B
  u32x4*  meta   = (u32x4*)(ws + 18722048);           // 20,480,000 B (64-aligned)

  // zero counts + ctr (agg zeroed inside k_pre)
  hipError_t _e = hipMemsetAsync(counts, 0, 80064, stream); (void)_e;

  k_pre  <<<HIST_BLOCKS + YN_BLOCKS + AGGZ_BLOCKS, 256, 0, stream>>>(
            edge_index, counts, node_input, node_attr, W_l1_0, W_l1_1,
            y, (float4*)agg);
  k_alloc<<<(N_NODES+255)/256, 256, 0, stream>>>(counts, ctr, cursor);
  k_fill <<<(N_EDGES+255)/256, 256, 0, stream>>>(edge_index, edge_attr, edge_scalars,
                                                 cursor, meta);
  k_edge <<<768, 256, 0, stream>>>((const uint2*)meta, W_fc0, W_fc1, y, agg);
  k_finish<<<YN_BLOCKS, 256, 0, stream>>>(node_input, node_attr, W_sc0, W_sc1,
                                          W_l2_0, W_l2_1, agg, out);
}